// Round 14
// baseline (124.325 us; speedup 1.0000x reference)
//
#include <hip/hip_runtime.h>

#define T_ 2048
#define B_ 2
#define H_ 12
#define C_ 768
#define M_ 4096  // B*T
#define BH_ (B_ * H_)
#define RSTR 2200  // reversed-e padded stride

typedef __attribute__((ext_vector_type(4))) float f32x4;
typedef __attribute__((ext_vector_type(16))) float f32x16;
typedef __attribute__((ext_vector_type(8))) __bf16 bf16x8;
typedef __attribute__((ext_vector_type(4))) __bf16 bf16x4;

// async global->LDS, 16B per lane; LDS dest wave-uniform base + lane*16
#define GLOAD16(GP, LP)                                                   \
  __builtin_amdgcn_global_load_lds(                                       \
      (__attribute__((address_space(1))) void*)(GP),                      \
      (__attribute__((address_space(3))) void*)(LP), 16, 0, 0)

// Packed fragment-major layouts (coalesced MFMA frag loads):
//  Qp/Kp: [bh][tile=t>>5][kc=d>>4][lane=((d>>3)&1)*32 + (t&31)][j=d&7]
//  Vp:    [bh][chunk=t>>6][dhalf=d>>5][kc=(t&63)>>4][lane=(((t&63)>>3)&1)*32+(d&31)][j=t&7]

// ---------------------------------------------------------------------------
// cvt3: one-shot fp32 -> bf16 for x, c_attn, c_proj. Also zeroes cnt[24]
// (ticket counters for the fused softmax; re-zeroed every call).
// ---------------------------------------------------------------------------
__global__ __launch_bounds__(256) void cvt3_k(const float* __restrict__ x,
                                              const float* __restrict__ ca,
                                              const float* __restrict__ cp,
                                              __bf16* __restrict__ xb,
                                              __bf16* __restrict__ wb,
                                              __bf16* __restrict__ pb,
                                              int* __restrict__ cnt) {
  const int id = blockIdx.x;
  if (id == 0 && threadIdx.x < BH_) cnt[threadIdx.x] = 0;
  const float* src;
  __bf16* dst;
  size_t base;
  if (id < 1536) { src = x; dst = xb; base = (size_t)id * 2048; }
  else if (id < 2400) { src = ca; dst = wb; base = (size_t)(id - 1536) * 2048; }
  else { src = cp; dst = pb; base = (size_t)(id - 2400) * 2048; }
  const size_t o = base + (size_t)threadIdx.x * 8;
  f32x4 v0 = *(const f32x4*)(src + o);
  f32x4 v1 = *(const f32x4*)(src + o + 4);
  bf16x8 r;
#pragma unroll
  for (int j = 0; j < 4; ++j) { r[j] = (__bf16)v0[j]; r[4 + j] = (__bf16)v1[j]; }
  *(bf16x8*)(dst + o) = r;
}

// ---------------------------------------------------------------------------
// Stage-1 GEMM (bf16): qkv = xb @ wb^T -> packed Qp, Kp, Vp.
// Operand-swap for Q/K blocks; isV branch hoisted out of the K-loop (R11).
// ---------------------------------------------------------------------------
__global__ __launch_bounds__(256) void gemm_qkv(const __bf16* __restrict__ A,
                                                const __bf16* __restrict__ Bm,
                                                __bf16* __restrict__ Qp,
                                                __bf16* __restrict__ Kp,
                                                __bf16* __restrict__ Vp) {
  __shared__ __align__(16) __bf16 sA[4096];  // [128][32]
  __shared__ __align__(16) __bf16 sB[4096];
  const int tid = threadIdx.x;
  const int id = blockIdx.x;
  const int lg = (id & 7) * 72 + (id >> 3);  // bijective: 576 = 8*72
  const int m0 = (lg / 18) * 128, n0 = (lg % 18) * 128;
  const bool isV = (n0 >= 1536);
  const int lane = tid & 63, w = tid >> 6;
  const int wr = w >> 1, wc = w & 1;
  const int fr = lane & 15;
  const int ko = (lane >> 4) << 3;
  const int srow = lane >> 2, scol = (lane & 3) << 3;
  const __bf16* Ab = A + (size_t)(m0 + srow) * 768 + scol;
  const __bf16* Bb = Bm + (size_t)(n0 + srow) * 768 + scol;
  const int c0 = 2 * w, c1 = 2 * w + 1;
  f32x4 acc[4][4] = {};

  if (isV) {
    for (int k0 = 0; k0 < 768; k0 += 32) {
      GLOAD16(Ab + (size_t)c0 * 16 * 768 + k0, &sA[c0 * 512]);
      GLOAD16(Ab + (size_t)c1 * 16 * 768 + k0, &sA[c1 * 512]);
      GLOAD16(Bb + (size_t)c0 * 16 * 768 + k0, &sB[c0 * 512]);
      GLOAD16(Bb + (size_t)c1 * 16 * 768 + k0, &sB[c1 * 512]);
      __syncthreads();
      bf16x8 a[4], b[4];
#pragma unroll
      for (int m = 0; m < 4; ++m) a[m] = *(const bf16x8*)&sA[(wr * 64 + m * 16 + fr) * 32 + ko];
#pragma unroll
      for (int n = 0; n < 4; ++n) b[n] = *(const bf16x8*)&sB[(wc * 64 + n * 16 + fr) * 32 + ko];
#pragma unroll
      for (int m = 0; m < 4; ++m)
#pragma unroll
        for (int n = 0; n < 4; ++n)
          acc[m][n] = __builtin_amdgcn_mfma_f32_16x16x32_bf16(a[m], b[n], acc[m][n], 0, 0, 0);
      __syncthreads();
    }
    const int orow = (lane >> 4) << 2, ocol = lane & 15;
#pragma unroll
    for (int m = 0; m < 4; ++m)
#pragma unroll
      for (int n = 0; n < 4; ++n) {
        int r = m0 + wr * 64 + m * 16 + orow;  // token (4 consecutive via j)
        int c = n0 + wc * 64 + n * 16 + ocol;  // feature
        int hd = c - 1536;
        int h = hd >> 6, d = hd & 63;
        int b = r >> 11, t = r & 2047;
        int bh = b * H_ + h;
        int chunk = t >> 6, sk = t & 63;
        int kc = sk >> 4, hf = (sk >> 3) & 1, j0 = sk & 7;  // j0 in {0,4}
        bf16x4 pk;
#pragma unroll
        for (int j = 0; j < 4; ++j) pk[j] = (__bf16)acc[m][n][j];
        *(bf16x4*)(Vp + ((size_t)bh * 32 + chunk) * 4096 + (d >> 5) * 2048 +
                   kc * 512 + (hf * 32 + (d & 31)) * 8 + j0) = pk;
      }
  } else {
    for (int k0 = 0; k0 < 768; k0 += 32) {
      GLOAD16(Ab + (size_t)c0 * 16 * 768 + k0, &sA[c0 * 512]);
      GLOAD16(Ab + (size_t)c1 * 16 * 768 + k0, &sA[c1 * 512]);
      GLOAD16(Bb + (size_t)c0 * 16 * 768 + k0, &sB[c0 * 512]);
      GLOAD16(Bb + (size_t)c1 * 16 * 768 + k0, &sB[c1 * 512]);
      __syncthreads();
      bf16x8 a[4], b[4];
#pragma unroll
      for (int m = 0; m < 4; ++m) a[m] = *(const bf16x8*)&sA[(wr * 64 + m * 16 + fr) * 32 + ko];
#pragma unroll
      for (int n = 0; n < 4; ++n) b[n] = *(const bf16x8*)&sB[(wc * 64 + n * 16 + fr) * 32 + ko];
#pragma unroll
      for (int m = 0; m < 4; ++m)
#pragma unroll
        for (int n = 0; n < 4; ++n)
          acc[m][n] = __builtin_amdgcn_mfma_f32_16x16x32_bf16(b[n], a[m], acc[m][n], 0, 0, 0);
      __syncthreads();
    }
    const int tcol = lane & 15, dbase = (lane >> 4) << 2;
#pragma unroll
    for (int m = 0; m < 4; ++m)
#pragma unroll
      for (int n = 0; n < 4; ++n) {
        int t4 = m0 + wr * 64 + m * 16 + tcol;   // token (fixed per frag)
        int c = n0 + wc * 64 + n * 16 + dbase;   // feature (4 consecutive via j)
        int sec = c / 768;
        int hd = c - sec * 768;
        int h = hd >> 6, d = hd & 63;
        int b = t4 >> 11, t = t4 & 2047;
        int bh = b * H_ + h;
        int tile = t >> 5, rr = t & 31;
        int kc = d >> 4, half = (d >> 3) & 1, dj = d & 7;  // dj in {0,4}
        bf16x4 pk;
#pragma unroll
        for (int j = 0; j < 4; ++j) pk[j] = (__bf16)acc[m][n][j];
        *(bf16x4*)((sec == 0 ? Qp : Kp) + ((size_t)bh * 64 + tile) * 2048 +
                   kc * 512 + (half * 32 + rr) * 8 + dj) = pk;
      }
  }
}

// ---------------------------------------------------------------------------
// Stage-2 GEMM (bf16 in, fp32 out): out = y2b @ pb^T. 64x64 tiles.
// ---------------------------------------------------------------------------
__global__ __launch_bounds__(256) void gemm_out(const __bf16* __restrict__ A,
                                                const __bf16* __restrict__ Bm,
                                                float* __restrict__ C) {
  __shared__ __align__(16) __bf16 sA[2048];  // [64][32]
  __shared__ __align__(16) __bf16 sB[2048];
  const int tid = threadIdx.x;
  const int id = blockIdx.x;
  const int lg = (id & 7) * 96 + (id >> 3);  // bijective: 768 = 8*96
  const int m0 = (lg / 12) * 64, n0 = (lg % 12) * 64;
  const int lane = tid & 63, w = tid >> 6;
  const int wr = w >> 1, wc = w & 1;
  const int fr = lane & 15;
  const int ko = (lane >> 4) << 3;
  const int srow = tid >> 2, scol = (tid & 3) << 3;
  const __bf16* Ab = A + (size_t)(m0 + srow) * 768 + scol;
  const __bf16* Bb = Bm + (size_t)(n0 + srow) * 768 + scol;
  f32x4 acc[2][2] = {};
  for (int k0 = 0; k0 < 768; k0 += 32) {
    GLOAD16(Ab + k0, &sA[w * 512]);
    GLOAD16(Bb + k0, &sB[w * 512]);
    __syncthreads();
    bf16x8 a[2], b[2];
#pragma unroll
    for (int m = 0; m < 2; ++m) a[m] = *(const bf16x8*)&sA[(wr * 32 + m * 16 + fr) * 32 + ko];
#pragma unroll
    for (int n = 0; n < 2; ++n) b[n] = *(const bf16x8*)&sB[(wc * 32 + n * 16 + fr) * 32 + ko];
#pragma unroll
    for (int m = 0; m < 2; ++m)
#pragma unroll
      for (int n = 0; n < 2; ++n)
        acc[m][n] = __builtin_amdgcn_mfma_f32_16x16x32_bf16(a[m], b[n], acc[m][n], 0, 0, 0);
    __syncthreads();
  }
  const int orow = (lane >> 4) << 2, ocol = lane & 15;
#pragma unroll
  for (int m = 0; m < 2; ++m)
#pragma unroll
    for (int n = 0; n < 2; ++n) {
      int r = m0 + wr * 32 + m * 16 + orow;
      int c = n0 + wc * 32 + n * 16 + ocol;
#pragma unroll
      for (int j = 0; j < 4; ++j) C[(size_t)(r + j) * 768 + c] = acc[m][n][j];
    }
}

// ---------------------------------------------------------------------------
// corr_k3: diagonal-band MFMA with LDS-shared operands + FUSED SOFTMAX.
// After writing its P36 slice, each block releases (syncthreads -> tid0
// threadfence -> atomicAdd ticket). The 36th arrival for a bh acquires and
// runs the softmax for that bh (fixed-order 36-slice sum -> deterministic
// bits regardless of which block wins). grid = 864.
// ---------------------------------------------------------------------------
__global__ __launch_bounds__(256) void corr_k3(const __bf16* __restrict__ Qp,
                                               const __bf16* __restrict__ Kp,
                                               float* __restrict__ P36,
                                               const float* __restrict__ temp,
                                               __bf16* __restrict__ Rb,
                                               float* __restrict__ zinv,
                                               int* __restrict__ cnt) {
  __shared__ __align__(16) char smem[40960];  // sQ 4KB + sK 9x4KB
  __shared__ int winls;
  __bf16* sQ = (__bf16*)smem;                 // 2048 elems
  __bf16* sK = (__bf16*)(smem + 4096);        // 9 slots x 2048 elems
  const int tid = threadIdx.x;
  int id = blockIdx.x;
  int sub = id >> 3;
  const int bh = (id & 7) * 3 + sub / 36;
  const int pi = sub % 36;
  int x = pi, qb = 0;
  while (x >= 8 - qb) { x -= 8 - qb; ++qb; }
  const int tc = qb + x;
  const int lane = tid & 63, w = tid >> 6;

  const __bf16* qbase = Qp + ((size_t)bh << 17);
  const __bf16* kbase = Kp + ((size_t)bh << 17);
  const int wq = w << 9;  // wave quarter offset in elems (w*512)

  const int smin = 8 * (tc - qb) - 8;
#pragma unroll
  for (int li = 0; li < 8; ++li) {
    int si = smin + li;
    if (si >= 0) GLOAD16(kbase + (size_t)si * 2048 + tid * 8, sK + li * 2048 + wq);
  }

  int r0 = 8 - 2 * w;
  int r1 = 7 - 2 * w;
  int ss = 8;
  const int qA = 8 * qb + 2 * w;
  f32x16 acc0 = {}, acc1 = {};

  for (int tau = 0; tau < 8; ++tau) {
    const int ti = 8 * tc + tau;
    GLOAD16(qbase + (size_t)ti * 2048 + tid * 8, sQ + wq);
    GLOAD16(kbase + (size_t)(ti - 8 * qb) * 2048 + tid * 8, sK + ss * 2048 + wq);
    __syncthreads();
    bf16x8 qv[4];
    const __bf16* qf = sQ + lane * 8;
#pragma unroll
    for (int kc = 0; kc < 4; ++kc) qv[kc] = *(const bf16x8*)(qf + kc * 512);
    const int si0 = ti - qA;
    if (si0 >= 0) {
      const __bf16* kf = sK + r0 * 2048 + lane * 8;
#pragma unroll
      for (int kc = 0; kc < 4; ++kc)
        acc0 = __builtin_amdgcn_mfma_f32_32x32x16_bf16(qv[kc], *(const bf16x8*)(kf + kc * 512), acc0, 0, 0, 0);
    }
    if (si0 - 1 >= 0) {
      const __bf16* kf = sK + r1 * 2048 + lane * 8;
#pragma unroll
      for (int kc = 0; kc < 4; ++kc)
        acc1 = __builtin_amdgcn_mfma_f32_32x32x16_bf16(qv[kc], *(const bf16x8*)(kf + kc * 512), acc1, 0, 0, 0);
    }
    __syncthreads();
    if (++r0 == 9) r0 = 0;
    if (++r1 == 9) r1 = 0;
    if (++ss == 9) ss = 0;
  }

  // ---- atomic-free diagonal reduction (aliases staging LDS) ----
  float* tile = (float*)smem;            // [4][1056]
  float* prow = (float*)(smem + 16896);  // [4][288]
  for (int i = tid; i < 1152; i += 256) prow[i] = 0.f;
  const int col = lane & 31, hi = lane >> 5;
  const int d = lane - 31;
#pragma unroll
  for (int b01 = 0; b01 < 2; ++b01) {
    const f32x16* ac = (b01 == 0) ? &acc0 : &acc1;
#pragma unroll
    for (int j = 0; j < 16; ++j) {
      int row = (j & 3) + ((j >> 2) << 3) + 4 * hi;
      tile[w * 1056 + row * 33 + col] = (*ac)[j];
    }
    __syncthreads();
    if (lane < 63) {
      float s = 0.f;
#pragma unroll
      for (int c = 0; c < 32; ++c) {
        int r = c + d;
        bool ok = (unsigned)r < 32u;
        float val = tile[w * 1056 + (ok ? r : 0) * 33 + c];
        s += ok ? val : 0.f;
      }
      prow[w * 288 + 32 * (2 * w + b01) + d + 32] += s;
    }
    __syncthreads();
  }

  float* Pd = P36 + ((size_t)pi * BH_ + bh) * T_;
  float ov[8];
#pragma unroll
  for (int u = 0; u < 8; ++u) {
    int L = (tid << 3) + u;
    int l = L - 256 * qb;
    float s = 0.f;
    if (l >= -31 && l < 256)
      s = prow[l + 32] + prow[288 + l + 32] + prow[576 + l + 32] + prow[864 + l + 32];
    ov[u] = s;
  }
  *(f32x4*)(Pd + (tid << 3)) = *(f32x4*)&ov[0];
  *(f32x4*)(Pd + (tid << 3) + 4) = *(f32x4*)&ov[4];

  // ---- ticket: last block for this bh runs the softmax ----
  __syncthreads();  // all P-row writes issued & drained (vmcnt in barrier)
  if (tid == 0) {
    __threadfence();  // release: block's P-row device-visible
    winls = (atomicAdd(&cnt[bh], 1) == 35);
  }
  __syncthreads();
  if (!winls) return;
  __threadfence();  // acquire: other blocks' P-rows visible

  float* se = (float*)smem;             // 2048 floats
  float* lm = (float*)(smem + 8192);    // 4
  float* wsum = (float*)(smem + 8208);  // 4
  const int wid = tid >> 6;
  const float scale = 1.0f / (64.0f * (temp[0] + 1e-6f));
  f32x4 sa = {}, sb = {};
#pragma unroll
  for (int j = 0; j < 36; ++j) {
    const float* pp = P36 + ((size_t)j * BH_ + bh) * T_ + (tid << 3);
    sa += *(const f32x4*)pp;
    sb += *(const f32x4*)(pp + 4);
  }
  float v[8];
#pragma unroll
  for (int i = 0; i < 4; ++i) { v[i] = sa[i] * scale; v[4 + i] = sb[i] * scale; }
  float m = v[0];
#pragma unroll
  for (int i = 1; i < 8; ++i) m = fmaxf(m, v[i]);
#pragma unroll
  for (int off = 1; off < 64; off <<= 1) m = fmaxf(m, __shfl_xor(m, off));
  if (lane == 0) lm[wid] = m;
  __syncthreads();
  m = fmaxf(fmaxf(lm[0], lm[1]), fmaxf(lm[2], lm[3]));
  float ex[8], pr[8], run = 0;
#pragma unroll
  for (int i = 0; i < 8; ++i) { ex[i] = __expf(v[i] - m); run += ex[i]; pr[i] = run; }
  float s = run;
  for (int off = 1; off < 64; off <<= 1) {
    float o = __shfl_up(s, off);
    if (lane >= off) s += o;
  }
  if (lane == 63) wsum[wid] = s;
  __syncthreads();
  float base = s - run;
  for (int jw = 0; jw < wid; ++jw) base += wsum[jw];
#pragma unroll
  for (int i = 0; i < 8; ++i) {
    int t = (tid << 3) + i;
    zinv[(size_t)bh * T_ + t] = 1.0f / (base + pr[i]);
    se[t] = ex[i];
  }
  __syncthreads();
  __bf16* rb = Rb + (size_t)bh * 8 * RSTR;
  for (int c = tid; c < RSTR / 8; c += 256) {
    int i0 = c << 3;
#pragma unroll
    for (int p = 0; p < 8; ++p) {
      bf16x8 ovv;
#pragma unroll
      for (int e = 0; e < 8; ++e) {
        int idx = T_ - 1 - p - (i0 + e);
        ovv[e] = (__bf16)((idx >= 0) ? se[idx] : 0.f);
      }
      *(bf16x8*)(rb + p * RSTR + i0) = ovv;
    }
  }
}

// ---------------------------------------------------------------------------
// conv_k (R12 form, 256 threads): Toeplitz MFMA, triple-buffered V-chunk
// pipeline; writes y2b (bf16). grid = 384 = 8 x (3 bh x 16 pairs).
// ---------------------------------------------------------------------------
__global__ __launch_bounds__(256) void conv_k(const __bf16* __restrict__ Vp,
                                              const __bf16* __restrict__ Rb,
                                              const float* __restrict__ zinv,
                                              __bf16* __restrict__ y2b) {
  __shared__ __align__(16) __bf16 revc[8 * RSTR];
  const int tid = threadIdx.x;
  int id = blockIdx.x;
  int sub = id >> 3;
  const int bh = (id & 7) * 3 + (sub >> 4);
  const int pr = sub & 15;
  const int lane = tid & 63, w = tid >> 6;

  const __bf16* rb = Rb + (size_t)bh * 8 * RSTR;
  for (int c = tid; c < RSTR; c += 256)
    *(bf16x8*)&revc[c << 3] = *(const bf16x8*)(rb + ((size_t)c << 3));
  __syncthreads();

  const int fr = lane & 31, kg = (lane >> 5) << 3;
  const int tt = (w < 2) ? (64 * pr + 32 * w) : (64 * (31 - pr) + 32 * (w - 2));
  const int trow = tt + fr;
  const int pp = (T_ - 1 - trow) & 7;
  const int obase = (T_ - 1 - trow) - pp;
  const __bf16* vpb = Vp + (size_t)bh * 131072 + (lane << 3);
  f32x16 acc0 = {}, acc1 = {};
  const int nst = (tt >> 6) + 1;

  bf16x8 A00, A01, A02, A03, A10, A11, A12, A13;
  bf16x8 B00, B01, B02, B03, B10, B11, B12, B13;
  bf16x8 C00, C01, C02, C03, C10, C11, C12, C13;

#define LOADV(P, CH)                                                          \
  {                                                                           \
    const __bf16* vb_ = vpb + (size_t)(CH) * 4096;                            \
    P##00 = *(const bf16x8*)(vb_);          P##01 = *(const bf16x8*)(vb_ + 512);  \
    P##02 = *(const bf16x8*)(vb_ + 1024);   P##03 = *(const bf16x8*)(vb_ + 1536); \
    P##10 = *(const bf16x8*)(vb_ + 2048);   P##11 = *(const bf16x8*)(vb_ + 2560); \
    P##12 = *(const bf16x8*)(vb_ + 3072);   P##13 = *(const bf16x8*)(vb_ + 3584); \
  }
#define MSTEP(P, ST)                                                          \
  {                                                                           \
    const int ab_ = pp * RSTR + obase + (ST) * 64 + kg;                       \
    bf16x8 a0_ = *(const bf16x8*)&revc[ab_];                                  \
    bf16x8 a1_ = *(const bf16x8*)&revc[ab_ + 16];                             \
    bf16x8 a2_ = *(const bf16x8*)&revc[ab_ + 32];                             \
    bf16x8 a3_ = *(const bf16x8*)&revc[ab_ + 48];                             \
    acc0 = __builtin_amdgcn_mfma_f32_32x32x16_bf16(a0_, P##00, acc0, 0, 0, 0);\
    acc1 = __builtin_amdgcn_mfma_f32_32x32x16_bf16(a0_, P##10, acc1, 0, 0, 0);\
    acc0 = __builtin_amdgcn_mfma_f32_32x32x16_bf16(a1_, P##01, acc0, 0, 0, 0);\
    acc1 = __builtin_amdgcn_mfma_f32_32x32x16_bf16(a1_, P##11, acc1, 0, 0, 0);\
    acc0 = __builtin_amdgcn_mfma_f32_32x32x16_bf16(a2_, P##02, acc0, 0, 0, 0);\
    acc1 = __builtin_amdgcn_mfma_f32_32x32x16_bf16(a2_, P##12, acc1, 0, 0, 0);\
    acc0 = __builtin_amdgcn_mfma_f32_32x32x16_bf16(a3_, P##03, acc0, 0, 0, 0);\
    acc1 = __builtin_amdgcn_mfma_f32_32x32x16_bf16(a3_, P##13, acc1, 0, 0, 0);\
  }

  LOADV(A, 0);
  if (nst > 1) LOADV(B, 1);
  if (nst > 2) LOADV(C, 2);
  int st = 0;
  while (true) {
    MSTEP(A, st); if (st + 3 < nst) LOADV(A, st + 3); if (++st >= nst) break;
    MSTEP(B, st); if (st + 3 < nst) LOADV(B, st + 3); if (++st >= nst) break;
    MSTEP(C, st); if (st + 3 < nst) LOADV(C, st + 3); if (++st >= nst) break;
  }
#undef LOADV
#undef MSTEP

  const int b = bh / H_, h = bh % H_;
  const int ocol = lane & 31, rbj = (lane >> 5) << 2;
  const float* zp = zinv + (size_t)bh * T_;
#pragma unroll
  for (int j = 0; j < 16; ++j) {
    int row = (j & 3) + ((j >> 2) << 3) + rbj;
    int t = tt + row;
    float zi = zp[t];
    __bf16* yr = y2b + ((size_t)b * T_ + t) * C_ + h * 64;
    yr[ocol] = (__bf16)(acc0[j] * zi);
    yr[32 + ocol] = (__bf16)(acc1[j] * zi);
  }
}

// ---------------------------------------------------------------------------
extern "C" void kernel_launch(void* const* d_in, const int* in_sizes, int n_in,
                              void* d_out, int out_size, void* d_ws, size_t ws_size,
                              hipStream_t stream) {
  const float* x = (const float*)d_in[0];
  const float* c_attn = (const float*)d_in[1];
  const float* c_proj = (const float*)d_in[2];
  const float* temp = (const float*)d_in[3];
  float* out = (float*)d_out;

  // ws (elems): Qp|Kp|Vp bf16 | Rb bf16 | zinv f32 | P36 f32 | pb bf16 |
  // xb bf16 (aliased by y2b after gemm_qkv) | wb bf16 | cnt int.  ~38.0 MB.
  __bf16* Qp = (__bf16*)d_ws;
  __bf16* Kp = Qp + (size_t)3145728;
  __bf16* Vp = Kp + (size_t)3145728;
  __bf16* Rb = Vp + (size_t)3145728;            // 422400
  float* zinv = (float*)(Rb + 422400);          // 49152
  float* P36 = zinv + 49152;                    // 1769472
  __bf16* pb = (__bf16*)(P36 + 1769472);        // 589824
  __bf16* xb = pb + 589824;                     // 3145728
  __bf16* wb = xb + 3145728;                    // 1769472
  int* cnt = (int*)(wb + 1769472);              // 24
  __bf16* y2b = xb;                             // alias: xb dead after gemm_qkv

  cvt3_k<<<dim3(2688), 256, 0, stream>>>(x, c_attn, c_proj, xb, wb, pb, cnt);
  gemm_qkv<<<dim3(576), 256, 0, stream>>>(xb, wb, Qp, Kp, Vp);
  corr_k3<<<dim3(864), 256, 0, stream>>>(Qp, Kp, P36, temp, Rb, zinv, cnt);
  conv_k<<<dim3(384), 256, 0, stream>>>(Vp, Rb, zinv, y2b);
  gemm_out<<<dim3(768), 256, 0, stream>>>(y2b, pb, out);
}

// Round 15
// 91.341 us; speedup vs baseline: 1.3611x; 1.3611x over previous
//
#include <hip/hip_runtime.h>

#define T_ 2048
#define B_ 2
#define H_ 12
#define C_ 768
#define M_ 4096  // B*T
#define BH_ (B_ * H_)
#define RSTR 2200  // reversed-e padded stride

typedef __attribute__((ext_vector_type(4))) float f32x4;
typedef __attribute__((ext_vector_type(16))) float f32x16;
typedef __attribute__((ext_vector_type(8))) __bf16 bf16x8;
typedef __attribute__((ext_vector_type(4))) __bf16 bf16x4;

// async global->LDS, 16B per lane; LDS dest wave-uniform base + lane*16
#define GLOAD16(GP, LP)                                                   \
  __builtin_amdgcn_global_load_lds(                                       \
      (__attribute__((address_space(1))) void*)(GP),                      \
      (__attribute__((address_space(3))) void*)(LP), 16, 0, 0)

// Packed fragment-major layouts (coalesced MFMA frag loads):
//  Qp/Kp: [bh][tile=t>>5][kc=d>>4][lane=((d>>3)&1)*32 + (t&31)][j=d&7]
//  Vp:    [bh][chunk=t>>6][dhalf=d>>5][kc=(t&63)>>4][lane=(((t&63)>>3)&1)*32+(d&31)][j=t&7]

// ---------------------------------------------------------------------------
// cvt3: one-shot fp32 -> bf16 for x, c_attn, c_proj.
// ---------------------------------------------------------------------------
__global__ __launch_bounds__(256) void cvt3_k(const float* __restrict__ x,
                                              const float* __restrict__ ca,
                                              const float* __restrict__ cp,
                                              __bf16* __restrict__ xb,
                                              __bf16* __restrict__ wb,
                                              __bf16* __restrict__ pb) {
  const int id = blockIdx.x;
  const float* src;
  __bf16* dst;
  size_t base;
  if (id < 1536) { src = x; dst = xb; base = (size_t)id * 2048; }
  else if (id < 2400) { src = ca; dst = wb; base = (size_t)(id - 1536) * 2048; }
  else { src = cp; dst = pb; base = (size_t)(id - 2400) * 2048; }
  const size_t o = base + (size_t)threadIdx.x * 8;
  f32x4 v0 = *(const f32x4*)(src + o);
  f32x4 v1 = *(const f32x4*)(src + o + 4);
  bf16x8 r;
#pragma unroll
  for (int j = 0; j < 4; ++j) { r[j] = (__bf16)v0[j]; r[4 + j] = (__bf16)v1[j]; }
  *(bf16x8*)(dst + o) = r;
}

// ---------------------------------------------------------------------------
// Stage-1 GEMM (bf16): qkv = xb @ wb^T -> packed Qp, Kp, Vp.
// Operand-swap for Q/K blocks; isV branch hoisted out of the K-loop (R11).
// ---------------------------------------------------------------------------
__global__ __launch_bounds__(256) void gemm_qkv(const __bf16* __restrict__ A,
                                                const __bf16* __restrict__ Bm,
                                                __bf16* __restrict__ Qp,
                                                __bf16* __restrict__ Kp,
                                                __bf16* __restrict__ Vp) {
  __shared__ __align__(16) __bf16 sA[4096];  // [128][32]
  __shared__ __align__(16) __bf16 sB[4096];
  const int tid = threadIdx.x;
  const int id = blockIdx.x;
  const int lg = (id & 7) * 72 + (id >> 3);  // bijective: 576 = 8*72
  const int m0 = (lg / 18) * 128, n0 = (lg % 18) * 128;
  const bool isV = (n0 >= 1536);
  const int lane = tid & 63, w = tid >> 6;
  const int wr = w >> 1, wc = w & 1;
  const int fr = lane & 15;
  const int ko = (lane >> 4) << 3;
  const int srow = lane >> 2, scol = (lane & 3) << 3;
  const __bf16* Ab = A + (size_t)(m0 + srow) * 768 + scol;
  const __bf16* Bb = Bm + (size_t)(n0 + srow) * 768 + scol;
  const int c0 = 2 * w, c1 = 2 * w + 1;
  f32x4 acc[4][4] = {};

  if (isV) {
    for (int k0 = 0; k0 < 768; k0 += 32) {
      GLOAD16(Ab + (size_t)c0 * 16 * 768 + k0, &sA[c0 * 512]);
      GLOAD16(Ab + (size_t)c1 * 16 * 768 + k0, &sA[c1 * 512]);
      GLOAD16(Bb + (size_t)c0 * 16 * 768 + k0, &sB[c0 * 512]);
      GLOAD16(Bb + (size_t)c1 * 16 * 768 + k0, &sB[c1 * 512]);
      __syncthreads();
      bf16x8 a[4], b[4];
#pragma unroll
      for (int m = 0; m < 4; ++m) a[m] = *(const bf16x8*)&sA[(wr * 64 + m * 16 + fr) * 32 + ko];
#pragma unroll
      for (int n = 0; n < 4; ++n) b[n] = *(const bf16x8*)&sB[(wc * 64 + n * 16 + fr) * 32 + ko];
#pragma unroll
      for (int m = 0; m < 4; ++m)
#pragma unroll
        for (int n = 0; n < 4; ++n)
          acc[m][n] = __builtin_amdgcn_mfma_f32_16x16x32_bf16(a[m], b[n], acc[m][n], 0, 0, 0);
      __syncthreads();
    }
    const int orow = (lane >> 4) << 2, ocol = lane & 15;
#pragma unroll
    for (int m = 0; m < 4; ++m)
#pragma unroll
      for (int n = 0; n < 4; ++n) {
        int r = m0 + wr * 64 + m * 16 + orow;  // token (4 consecutive via j)
        int c = n0 + wc * 64 + n * 16 + ocol;  // feature
        int hd = c - 1536;
        int h = hd >> 6, d = hd & 63;
        int b = r >> 11, t = r & 2047;
        int bh = b * H_ + h;
        int chunk = t >> 6, sk = t & 63;
        int kc = sk >> 4, hf = (sk >> 3) & 1, j0 = sk & 7;  // j0 in {0,4}
        bf16x4 pk;
#pragma unroll
        for (int j = 0; j < 4; ++j) pk[j] = (__bf16)acc[m][n][j];
        *(bf16x4*)(Vp + ((size_t)bh * 32 + chunk) * 4096 + (d >> 5) * 2048 +
                   kc * 512 + (hf * 32 + (d & 31)) * 8 + j0) = pk;
      }
  } else {
    for (int k0 = 0; k0 < 768; k0 += 32) {
      GLOAD16(Ab + (size_t)c0 * 16 * 768 + k0, &sA[c0 * 512]);
      GLOAD16(Ab + (size_t)c1 * 16 * 768 + k0, &sA[c1 * 512]);
      GLOAD16(Bb + (size_t)c0 * 16 * 768 + k0, &sB[c0 * 512]);
      GLOAD16(Bb + (size_t)c1 * 16 * 768 + k0, &sB[c1 * 512]);
      __syncthreads();
      bf16x8 a[4], b[4];
#pragma unroll
      for (int m = 0; m < 4; ++m) a[m] = *(const bf16x8*)&sA[(wr * 64 + m * 16 + fr) * 32 + ko];
#pragma unroll
      for (int n = 0; n < 4; ++n) b[n] = *(const bf16x8*)&sB[(wc * 64 + n * 16 + fr) * 32 + ko];
#pragma unroll
      for (int m = 0; m < 4; ++m)
#pragma unroll
        for (int n = 0; n < 4; ++n)
          acc[m][n] = __builtin_amdgcn_mfma_f32_16x16x32_bf16(b[n], a[m], acc[m][n], 0, 0, 0);
      __syncthreads();
    }
    const int tcol = lane & 15, dbase = (lane >> 4) << 2;
#pragma unroll
    for (int m = 0; m < 4; ++m)
#pragma unroll
      for (int n = 0; n < 4; ++n) {
        int t4 = m0 + wr * 64 + m * 16 + tcol;   // token (fixed per frag)
        int c = n0 + wc * 64 + n * 16 + dbase;   // feature (4 consecutive via j)
        int sec = c / 768;
        int hd = c - sec * 768;
        int h = hd >> 6, d = hd & 63;
        int b = t4 >> 11, t = t4 & 2047;
        int bh = b * H_ + h;
        int tile = t >> 5, rr = t & 31;
        int kc = d >> 4, half = (d >> 3) & 1, dj = d & 7;  // dj in {0,4}
        bf16x4 pk;
#pragma unroll
        for (int j = 0; j < 4; ++j) pk[j] = (__bf16)acc[m][n][j];
        *(bf16x4*)((sec == 0 ? Qp : Kp) + ((size_t)bh * 64 + tile) * 2048 +
                   kc * 512 + (half * 32 + rr) * 8 + dj) = pk;
      }
  }
}

// ---------------------------------------------------------------------------
// Stage-2 GEMM (bf16 in, fp32 out): out = y2b @ pb^T. 64x64 tiles.
// ---------------------------------------------------------------------------
__global__ __launch_bounds__(256) void gemm_out(const __bf16* __restrict__ A,
                                                const __bf16* __restrict__ Bm,
                                                float* __restrict__ C) {
  __shared__ __align__(16) __bf16 sA[2048];  // [64][32]
  __shared__ __align__(16) __bf16 sB[2048];
  const int tid = threadIdx.x;
  const int id = blockIdx.x;
  const int lg = (id & 7) * 96 + (id >> 3);  // bijective: 768 = 8*96
  const int m0 = (lg / 12) * 64, n0 = (lg % 12) * 64;
  const int lane = tid & 63, w = tid >> 6;
  const int wr = w >> 1, wc = w & 1;
  const int fr = lane & 15;
  const int ko = (lane >> 4) << 3;
  const int srow = tid >> 2, scol = (tid & 3) << 3;
  const __bf16* Ab = A + (size_t)(m0 + srow) * 768 + scol;
  const __bf16* Bb = Bm + (size_t)(n0 + srow) * 768 + scol;
  f32x4 acc[2][2] = {};
  for (int k0 = 0; k0 < 768; k0 += 32) {
    GLOAD16(Ab + k0, &sA[w * 512]);
    GLOAD16(Bb + k0, &sB[w * 512]);
    __syncthreads();
    bf16x8 a[2], b[2];
#pragma unroll
    for (int m = 0; m < 2; ++m) a[m] = *(const bf16x8*)&sA[(wr * 32 + m * 16 + fr) * 32 + ko];
#pragma unroll
    for (int n = 0; n < 2; ++n) b[n] = *(const bf16x8*)&sB[(wc * 32 + n * 16 + fr) * 32 + ko];
#pragma unroll
    for (int m = 0; m < 2; ++m)
#pragma unroll
      for (int n = 0; n < 2; ++n)
        acc[m][n] = __builtin_amdgcn_mfma_f32_16x16x32_bf16(a[m], b[n], acc[m][n], 0, 0, 0);
    __syncthreads();
  }
  const int orow = (lane >> 4) << 2, ocol = lane & 15;
#pragma unroll
  for (int m = 0; m < 2; ++m)
#pragma unroll
    for (int n = 0; n < 2; ++n) {
      int r = m0 + wr * 32 + m * 16 + orow;
      int c = n0 + wc * 32 + n * 16 + ocol;
#pragma unroll
      for (int j = 0; j < 4; ++j) C[(size_t)(r + j) * 768 + c] = acc[m][n][j];
    }
}

// ---------------------------------------------------------------------------
// corr_k3: diagonal-band MFMA with LDS-shared operands (R12 proven form).
// grid = 864 = 8 XCD x (3 bh x 36 (qb,tc) pairs).
// ---------------------------------------------------------------------------
__global__ __launch_bounds__(256) void corr_k3(const __bf16* __restrict__ Qp,
                                               const __bf16* __restrict__ Kp,
                                               float* __restrict__ P36) {
  __shared__ __align__(16) char smem[40960];  // sQ 4KB + sK 9x4KB
  __bf16* sQ = (__bf16*)smem;                 // 2048 elems
  __bf16* sK = (__bf16*)(smem + 4096);        // 9 slots x 2048 elems
  const int tid = threadIdx.x;
  int id = blockIdx.x;
  int sub = id >> 3;
  const int bh = (id & 7) * 3 + sub / 36;
  const int pi = sub % 36;
  int x = pi, qb = 0;
  while (x >= 8 - qb) { x -= 8 - qb; ++qb; }
  const int tc = qb + x;
  const int lane = tid & 63, w = tid >> 6;

  const __bf16* qbase = Qp + ((size_t)bh << 17);
  const __bf16* kbase = Kp + ((size_t)bh << 17);
  const int wq = w << 9;  // wave quarter offset in elems (w*512)

  const int smin = 8 * (tc - qb) - 8;
#pragma unroll
  for (int li = 0; li < 8; ++li) {
    int si = smin + li;
    if (si >= 0) GLOAD16(kbase + (size_t)si * 2048 + tid * 8, sK + li * 2048 + wq);
  }

  int r0 = 8 - 2 * w;
  int r1 = 7 - 2 * w;
  int ss = 8;
  const int qA = 8 * qb + 2 * w;
  f32x16 acc0 = {}, acc1 = {};

  for (int tau = 0; tau < 8; ++tau) {
    const int ti = 8 * tc + tau;
    GLOAD16(qbase + (size_t)ti * 2048 + tid * 8, sQ + wq);
    GLOAD16(kbase + (size_t)(ti - 8 * qb) * 2048 + tid * 8, sK + ss * 2048 + wq);
    __syncthreads();
    bf16x8 qv[4];
    const __bf16* qf = sQ + lane * 8;
#pragma unroll
    for (int kc = 0; kc < 4; ++kc) qv[kc] = *(const bf16x8*)(qf + kc * 512);
    const int si0 = ti - qA;
    if (si0 >= 0) {
      const __bf16* kf = sK + r0 * 2048 + lane * 8;
#pragma unroll
      for (int kc = 0; kc < 4; ++kc)
        acc0 = __builtin_amdgcn_mfma_f32_32x32x16_bf16(qv[kc], *(const bf16x8*)(kf + kc * 512), acc0, 0, 0, 0);
    }
    if (si0 - 1 >= 0) {
      const __bf16* kf = sK + r1 * 2048 + lane * 8;
#pragma unroll
      for (int kc = 0; kc < 4; ++kc)
        acc1 = __builtin_amdgcn_mfma_f32_32x32x16_bf16(qv[kc], *(const bf16x8*)(kf + kc * 512), acc1, 0, 0, 0);
    }
    __syncthreads();
    if (++r0 == 9) r0 = 0;
    if (++r1 == 9) r1 = 0;
    if (++ss == 9) ss = 0;
  }

  // ---- atomic-free diagonal reduction (aliases staging LDS) ----
  float* tile = (float*)smem;            // [4][1056]
  float* prow = (float*)(smem + 16896);  // [4][288]
  for (int i = tid; i < 1152; i += 256) prow[i] = 0.f;
  const int col = lane & 31, hi = lane >> 5;
  const int d = lane - 31;
#pragma unroll
  for (int b01 = 0; b01 < 2; ++b01) {
    const f32x16* ac = (b01 == 0) ? &acc0 : &acc1;
#pragma unroll
    for (int j = 0; j < 16; ++j) {
      int row = (j & 3) + ((j >> 2) << 3) + 4 * hi;
      tile[w * 1056 + row * 33 + col] = (*ac)[j];
    }
    __syncthreads();
    if (lane < 63) {
      float s = 0.f;
#pragma unroll
      for (int c = 0; c < 32; ++c) {
        int r = c + d;
        bool ok = (unsigned)r < 32u;
        float val = tile[w * 1056 + (ok ? r : 0) * 33 + c];
        s += ok ? val : 0.f;
      }
      prow[w * 288 + 32 * (2 * w + b01) + d + 32] += s;
    }
    __syncthreads();
  }

  float* Pd = P36 + ((size_t)pi * BH_ + bh) * T_;
  float ov[8];
#pragma unroll
  for (int u = 0; u < 8; ++u) {
    int L = (tid << 3) + u;
    int l = L - 256 * qb;
    float s = 0.f;
    if (l >= -31 && l < 256)
      s = prow[l + 32] + prow[288 + l + 32] + prow[576 + l + 32] + prow[864 + l + 32];
    ov[u] = s;
  }
  *(f32x4*)(Pd + (tid << 3)) = *(f32x4*)&ov[0];
  *(f32x4*)(Pd + (tid << 3) + 4) = *(f32x4*)&ov[4];
}

// ---------------------------------------------------------------------------
// soft_k: reduce 36 partial slices -> Rb (phase-shifted reversed-e) + zinv.
// ---------------------------------------------------------------------------
__global__ __launch_bounds__(256) void soft_k(const float* __restrict__ P,
                                              const float* __restrict__ temp,
                                              __bf16* __restrict__ Rb,
                                              float* __restrict__ zinv) {
  __shared__ float se[T_];
  __shared__ float lm[4], wsum[4];
  const int bh = blockIdx.x, tid = threadIdx.x;
  const int lane = tid & 63, wid = tid >> 6;
  const float scale = 1.0f / (64.0f * (temp[0] + 1e-6f));
  f32x4 sa = {}, sb = {};
#pragma unroll
  for (int j = 0; j < 36; ++j) {
    const float* pp = P + ((size_t)j * BH_ + bh) * T_ + (tid << 3);
    sa += *(const f32x4*)pp;
    sb += *(const f32x4*)(pp + 4);
  }
  float v[8];
#pragma unroll
  for (int i = 0; i < 4; ++i) { v[i] = sa[i] * scale; v[4 + i] = sb[i] * scale; }
  float m = v[0];
#pragma unroll
  for (int i = 1; i < 8; ++i) m = fmaxf(m, v[i]);
#pragma unroll
  for (int off = 1; off < 64; off <<= 1) m = fmaxf(m, __shfl_xor(m, off));
  if (lane == 0) lm[wid] = m;
  __syncthreads();
  m = fmaxf(fmaxf(lm[0], lm[1]), fmaxf(lm[2], lm[3]));
  float ex[8], pr[8], run = 0;
#pragma unroll
  for (int i = 0; i < 8; ++i) { ex[i] = __expf(v[i] - m); run += ex[i]; pr[i] = run; }
  float s = run;
  for (int off = 1; off < 64; off <<= 1) {
    float o = __shfl_up(s, off);
    if (lane >= off) s += o;
  }
  if (lane == 63) wsum[wid] = s;
  __syncthreads();
  float base = s - run;
  for (int jw = 0; jw < wid; ++jw) base += wsum[jw];
#pragma unroll
  for (int i = 0; i < 8; ++i) {
    int t = (tid << 3) + i;
    zinv[(size_t)bh * T_ + t] = 1.0f / (base + pr[i]);
    se[t] = ex[i];
  }
  __syncthreads();
  __bf16* rb = Rb + (size_t)bh * 8 * RSTR;
  for (int c = tid; c < RSTR / 8; c += 256) {
    int i0 = c << 3;
#pragma unroll
    for (int p = 0; p < 8; ++p) {
      bf16x8 ovv;
#pragma unroll
      for (int e = 0; e < 8; ++e) {
        int idx = T_ - 1 - p - (i0 + e);
        ovv[e] = (__bf16)((idx >= 0) ? se[idx] : 0.f);
      }
      *(bf16x8*)(rb + p * RSTR + i0) = ovv;
    }
  }
}

// ---------------------------------------------------------------------------
// conv_k (R12 proven form, 256 threads): Toeplitz MFMA, triple-buffered
// V-chunk pipeline; writes y2b (bf16). grid = 384 = 8 x (3 bh x 16 pairs).
// ---------------------------------------------------------------------------
__global__ __launch_bounds__(256) void conv_k(const __bf16* __restrict__ Vp,
                                              const __bf16* __restrict__ Rb,
                                              const float* __restrict__ zinv,
                                              __bf16* __restrict__ y2b) {
  __shared__ __align__(16) __bf16 revc[8 * RSTR];
  const int tid = threadIdx.x;
  int id = blockIdx.x;
  int sub = id >> 3;
  const int bh = (id & 7) * 3 + (sub >> 4);
  const int pr = sub & 15;
  const int lane = tid & 63, w = tid >> 6;

  const __bf16* rb = Rb + (size_t)bh * 8 * RSTR;
  for (int c = tid; c < RSTR; c += 256)
    *(bf16x8*)&revc[c << 3] = *(const bf16x8*)(rb + ((size_t)c << 3));
  __syncthreads();

  const int fr = lane & 31, kg = (lane >> 5) << 3;
  const int tt = (w < 2) ? (64 * pr + 32 * w) : (64 * (31 - pr) + 32 * (w - 2));
  const int trow = tt + fr;
  const int pp = (T_ - 1 - trow) & 7;
  const int obase = (T_ - 1 - trow) - pp;
  const __bf16* vpb = Vp + (size_t)bh * 131072 + (lane << 3);
  f32x16 acc0 = {}, acc1 = {};
  const int nst = (tt >> 6) + 1;

  bf16x8 A00, A01, A02, A03, A10, A11, A12, A13;
  bf16x8 B00, B01, B02, B03, B10, B11, B12, B13;
  bf16x8 C00, C01, C02, C03, C10, C11, C12, C13;

#define LOADV(P, CH)                                                          \
  {                                                                           \
    const __bf16* vb_ = vpb + (size_t)(CH) * 4096;                            \
    P##00 = *(const bf16x8*)(vb_);          P##01 = *(const bf16x8*)(vb_ + 512);  \
    P##02 = *(const bf16x8*)(vb_ + 1024);   P##03 = *(const bf16x8*)(vb_ + 1536); \
    P##10 = *(const bf16x8*)(vb_ + 2048);   P##11 = *(const bf16x8*)(vb_ + 2560); \
    P##12 = *(const bf16x8*)(vb_ + 3072);   P##13 = *(const bf16x8*)(vb_ + 3584); \
  }
#define MSTEP(P, ST)                                                          \
  {                                                                           \
    const int ab_ = pp * RSTR + obase + (ST) * 64 + kg;                       \
    bf16x8 a0_ = *(const bf16x8*)&revc[ab_];                                  \
    bf16x8 a1_ = *(const bf16x8*)&revc[ab_ + 16];                             \
    bf16x8 a2_ = *(const bf16x8*)&revc[ab_ + 32];                             \
    bf16x8 a3_ = *(const bf16x8*)&revc[ab_ + 48];                             \
    acc0 = __builtin_amdgcn_mfma_f32_32x32x16_bf16(a0_, P##00, acc0, 0, 0, 0);\
    acc1 = __builtin_amdgcn_mfma_f32_32x32x16_bf16(a0_, P##10, acc1, 0, 0, 0);\
    acc0 = __builtin_amdgcn_mfma_f32_32x32x16_bf16(a1_, P##01, acc0, 0, 0, 0);\
    acc1 = __builtin_amdgcn_mfma_f32_32x32x16_bf16(a1_, P##11, acc1, 0, 0, 0);\
    acc0 = __builtin_amdgcn_mfma_f32_32x32x16_bf16(a2_, P##02, acc0, 0, 0, 0);\
    acc1 = __builtin_amdgcn_mfma_f32_32x32x16_bf16(a2_, P##12, acc1, 0, 0, 0);\
    acc0 = __builtin_amdgcn_mfma_f32_32x32x16_bf16(a3_, P##03, acc0, 0, 0, 0);\
    acc1 = __builtin_amdgcn_mfma_f32_32x32x16_bf16(a3_, P##13, acc1, 0, 0, 0);\
  }

  LOADV(A, 0);
  if (nst > 1) LOADV(B, 1);
  if (nst > 2) LOADV(C, 2);
  int st = 0;
  while (true) {
    MSTEP(A, st); if (st + 3 < nst) LOADV(A, st + 3); if (++st >= nst) break;
    MSTEP(B, st); if (st + 3 < nst) LOADV(B, st + 3); if (++st >= nst) break;
    MSTEP(C, st); if (st + 3 < nst) LOADV(C, st + 3); if (++st >= nst) break;
  }
#undef LOADV
#undef MSTEP

  const int b = bh / H_, h = bh % H_;
  const int ocol = lane & 31, rbj = (lane >> 5) << 2;
  const float* zp = zinv + (size_t)bh * T_;
#pragma unroll
  for (int j = 0; j < 16; ++j) {
    int row = (j & 3) + ((j >> 2) << 3) + rbj;
    int t = tt + row;
    float zi = zp[t];
    __bf16* yr = y2b + ((size_t)b * T_ + t) * C_ + h * 64;
    yr[ocol] = (__bf16)(acc0[j] * zi);
    yr[32 + ocol] = (__bf16)(acc1[j] * zi);
  }
}

// ---------------------------------------------------------------------------
extern "C" void kernel_launch(void* const* d_in, const int* in_sizes, int n_in,
                              void* d_out, int out_size, void* d_ws, size_t ws_size,
                              hipStream_t stream) {
  const float* x = (const float*)d_in[0];
  const float* c_attn = (const float*)d_in[1];
  const float* c_proj = (const float*)d_in[2];
  const float* temp = (const float*)d_in[3];
  float* out = (float*)d_out;

  // ws (elems): Qp|Kp|Vp bf16 | Rb bf16 | zinv f32 | P36 f32 | pb bf16 |
  // xb bf16 (aliased by y2b after gemm_qkv) | wb bf16.  ~38.0 MB.
  __bf16* Qp = (__bf16*)d_ws;
  __bf16* Kp = Qp + (size_t)3145728;
  __bf16* Vp = Kp + (size_t)3145728;
  __bf16* Rb = Vp + (size_t)3145728;            // 422400
  float* zinv = (float*)(Rb + 422400);          // 49152
  float* P36 = zinv + 49152;                    // 1769472
  __bf16* pb = (__bf16*)(P36 + 1769472);        // 589824
  __bf16* xb = pb + 589824;                     // 3145728
  __bf16* wb = xb + 3145728;                    // 1769472
  __bf16* y2b = xb;                             // alias: xb dead after gemm_qkv

  cvt3_k<<<dim3(2688), 256, 0, stream>>>(x, c_attn, c_proj, xb, wb, pb);
  gemm_qkv<<<dim3(576), 256, 0, stream>>>(xb, wb, Qp, Kp, Vp);
  corr_k3<<<dim3(864), 256, 0, stream>>>(Qp, Kp, P36);
  soft_k<<<dim3(BH_), 256, 0, stream>>>(P36, temp, Rb, zinv);
  conv_k<<<dim3(384), 256, 0, stream>>>(Vp, Rb, zinv, y2b);
  gemm_out<<<dim3(768), 256, 0, stream>>>(y2b, pb, out);
}